// Round 3
// baseline (46.301 us; speedup 1.0000x reference)
//
#include <hip/hip_runtime.h>
#include <hip/hip_bf16.h>

// ROIEmbedding1D: x [B=4096, W=16384] f32 -> out [B, 31] f32
// 31 = sum(N_BINS), N_BINS = [1,2,4,8,16]. W divisible by all p, bins nest:
// compute 16 segment maxima (1024 floats each), tree-reduce upward.
// Output row layout: [p1(1), p2(2), p4(4), p8(8), p16(16)].
// NOTE: reference output dtype is float32 (pure f32 jax graph) -> d_out is float*.

#define W_COLS 16384
#define F4_PER_ROW (W_COLS / 4)      // 4096 float4 per row
#define F4_PER_SEG (F4_PER_ROW / 16) // 256 float4 per 1024-float segment

__global__ __launch_bounds__(256) void roi_embed_v3_kernel(
    const float* __restrict__ x, float* __restrict__ out, int n_rows) {
    const int t   = threadIdx.x;   // 0..255
    const int seg = t >> 4;        // 0..15
    const int lis = t & 15;        // lane within segment

    __shared__ float red[256];

    for (int row = blockIdx.x; row < n_rows; row += gridDim.x) {
        const float4* xr =
            reinterpret_cast<const float4*>(x + (size_t)row * W_COLS);

        // Per-thread max over 16 float4 (stride 16) within its segment.
        // 16 lanes x 16B = 256B dense per group per iteration -> coalesced.
        float m = -INFINITY;
        const int base = seg * F4_PER_SEG + lis;
#pragma unroll
        for (int k = 0; k < 16; ++k) {
            float4 v = xr[base + k * 16];
            m = fmaxf(m, fmaxf(fmaxf(v.x, v.y), fmaxf(v.z, v.w)));
        }

        red[t] = m;
        __syncthreads();

        if (t == 0) {
            float s16[16];
#pragma unroll
            for (int i = 0; i < 16; ++i) {
                float s = red[i * 16];
#pragma unroll
                for (int j = 1; j < 16; ++j) s = fmaxf(s, red[i * 16 + j]);
                s16[i] = s;
            }
            float s8[8], s4[4], s2[2];
#pragma unroll
            for (int i = 0; i < 8; ++i) s8[i] = fmaxf(s16[2 * i], s16[2 * i + 1]);
#pragma unroll
            for (int i = 0; i < 4; ++i) s4[i] = fmaxf(s8[2 * i], s8[2 * i + 1]);
#pragma unroll
            for (int i = 0; i < 2; ++i) s2[i] = fmaxf(s4[2 * i], s4[2 * i + 1]);
            const float s1 = fmaxf(s2[0], s2[1]);

            float* o = out + (size_t)row * 31;
            o[0] = s1;
            o[1] = s2[0];
            o[2] = s2[1];
#pragma unroll
            for (int i = 0; i < 4; ++i)  o[3 + i]  = s4[i];
#pragma unroll
            for (int i = 0; i < 8; ++i)  o[7 + i]  = s8[i];
#pragma unroll
            for (int i = 0; i < 16; ++i) o[15 + i] = s16[i];
        }
        __syncthreads();  // red[] reuse safety for next grid-stride row
    }
}

extern "C" void kernel_launch(void* const* d_in, const int* in_sizes, int n_in,
                              void* d_out, int out_size, void* d_ws, size_t ws_size,
                              hipStream_t stream) {
    const float* x = (const float*)d_in[0];
    float* out = (float*)d_out;

    int B = (out_size > 0) ? (out_size / 31) : 0;
    if (B <= 0 && n_in > 0 && in_sizes && in_sizes[0] > 0) B = in_sizes[0] / W_COLS;
    if (B <= 0) B = 4096;  // static problem size from reference setup_inputs()

    roi_embed_v3_kernel<<<B, 256, 0, stream>>>(x, out, B);
}

// Round 4
// 44.081 us; speedup vs baseline: 1.0504x; 1.0504x over previous
//
#include <hip/hip_runtime.h>
#include <hip/hip_bf16.h>

// ROIEmbedding1D: x [B=4096, W=16384] f32 -> out [B, 31] f32
// N_BINS = [1,2,4,8,16]; bins nest -> compute 16 segment maxima (1024 floats
// each), tree-reduce upward. Row layout: [p1(1), p2(2), p4(4), p8(8), p16(16)].
//
// v4: wave-contiguous reads. Wave w owns quarter-row w (4096 floats); per
// iteration the 64 lanes read 64 consecutive float4 = one dense 1KB line.
// 64 float4 never cross a 256-float4 segment boundary, so iteration k feeds
// segment k>>2 (static index -> stays in registers).

#define W_COLS 16384
#define F4_PER_QTR 1024  // float4 per quarter-row

__global__ __launch_bounds__(256) void roi_embed_v4_kernel(
    const float* __restrict__ x, float* __restrict__ out, int n_rows) {
    const int t    = threadIdx.x;  // 0..255
    const int wave = t >> 6;       // 0..3
    const int lane = t & 63;

    __shared__ float segmax[16];

    for (int row = blockIdx.x; row < n_rows; row += gridDim.x) {
        const float4* xq =
            reinterpret_cast<const float4*>(x + (size_t)row * W_COLS) +
            wave * F4_PER_QTR;

        float acc[4] = {-INFINITY, -INFINITY, -INFINITY, -INFINITY};
#pragma unroll
        for (int k = 0; k < 16; ++k) {
            float4 v = xq[k * 64 + lane];
            float mv = fmaxf(fmaxf(v.x, v.y), fmaxf(v.z, v.w));
            acc[k >> 2] = fmaxf(acc[k >> 2], mv);  // k>>2 is compile-time
        }

        // 64-lane butterfly reduce each of the 4 segment accumulators.
#pragma unroll
        for (int j = 0; j < 4; ++j) {
#pragma unroll
            for (int off = 32; off >= 1; off >>= 1)
                acc[j] = fmaxf(acc[j], __shfl_xor(acc[j], off));
        }

        if (lane == 0) {
#pragma unroll
            for (int j = 0; j < 4; ++j) segmax[wave * 4 + j] = acc[j];
        }
        __syncthreads();

        if (t == 0) {
            float s16[16];
#pragma unroll
            for (int i = 0; i < 16; ++i) s16[i] = segmax[i];
            float s8[8], s4[4], s2[2];
#pragma unroll
            for (int i = 0; i < 8; ++i) s8[i] = fmaxf(s16[2 * i], s16[2 * i + 1]);
#pragma unroll
            for (int i = 0; i < 4; ++i) s4[i] = fmaxf(s8[2 * i], s8[2 * i + 1]);
#pragma unroll
            for (int i = 0; i < 2; ++i) s2[i] = fmaxf(s4[2 * i], s4[2 * i + 1]);
            const float s1 = fmaxf(s2[0], s2[1]);

            float* o = out + (size_t)row * 31;
            o[0] = s1;
            o[1] = s2[0];
            o[2] = s2[1];
#pragma unroll
            for (int i = 0; i < 4; ++i)  o[3 + i]  = s4[i];
#pragma unroll
            for (int i = 0; i < 8; ++i)  o[7 + i]  = s8[i];
#pragma unroll
            for (int i = 0; i < 16; ++i) o[15 + i] = s16[i];
        }
        __syncthreads();  // segmax[] reuse safety
    }
}

extern "C" void kernel_launch(void* const* d_in, const int* in_sizes, int n_in,
                              void* d_out, int out_size, void* d_ws, size_t ws_size,
                              hipStream_t stream) {
    const float* x = (const float*)d_in[0];
    float* out = (float*)d_out;

    int B = (out_size > 0) ? (out_size / 31) : 0;
    if (B <= 0 && n_in > 0 && in_sizes && in_sizes[0] > 0) B = in_sizes[0] / W_COLS;
    if (B <= 0) B = 4096;  // static problem size from reference setup_inputs()

    roi_embed_v4_kernel<<<B, 256, 0, stream>>>(x, out, B);
}